// Round 9
// baseline (187.152 us; speedup 1.0000x reference)
//
#include <hip/hip_runtime.h>
#include <hip/hip_bf16.h>

#define NQ     8
#define SEQL   128
#define BATCHN 256
#define EMBED  512
#define DIN    520          // EMBED + NQ
#define NROWS  (SEQL*BATCHN) // 32768
#define GSTR   32           // 4 gates * 8 qubits
#define INV2PI 0.15915494309189535f
#define WROW   524          // Wlds padded row (shorts)

#define K1BLK  128          // persistent producer blocks
#define NUNITS 512          // 64-row units
#define NCHUNK 16           // 8 timesteps per chunk
#define UNITS_PER_CHUNK 32

typedef __attribute__((ext_vector_type(8))) short  bf16x8;
typedef __attribute__((ext_vector_type(4))) float  f32x4;
typedef unsigned int uint2v __attribute__((ext_vector_type(2)));

__device__ unsigned int g_cnt[NCHUNK];

__device__ __forceinline__ short f2bf(float f) {
    union { __hip_bfloat16 h; short s; } u;
    u.h = __float2bfloat16(f);          // RNE convert
    return u.s;
}

// ---------------------------------------------------------------------------
// DPP helpers: row_shr:N -> lane i gets i-N ; row_shl:N -> i+N ;
//              row_ror:8 -> lane i gets i^8 within its 16-lane row
// ---------------------------------------------------------------------------
#define DPP_QP(a,b,c,d) ((a)|((b)<<2)|((c)<<4)|((d)<<6))
#define DPP_SHL(n) (0x100+(n))
#define DPP_SHR(n) (0x110+(n))
#define DPP_ROR(n) (0x120+(n))

template<int CTRL>
__device__ __forceinline__ float updpf(float old_, float src) {
    return __int_as_float(__builtin_amdgcn_update_dpp(
        __float_as_int(old_), __float_as_int(src), CTRL, 0xF, 0xF, false));
}

// value at lane^16 (XOR-extract, semantics-proof)
__device__ __forceinline__ float xor16f(float x) {
    unsigned xu = (unsigned)__float_as_int(x);
    uint2v r = __builtin_amdgcn_permlane16_swap(xu, xu, false, false);
    return __int_as_float((int)(r.x ^ r.y ^ xu));
}

__device__ __forceinline__ float frcp(float x) { return __builtin_amdgcn_rcpf(x); }
__device__ __forceinline__ float fexp2(float x) { return __builtin_amdgcn_exp2f(x); }

#define LOG2E  1.4426950408889634f
#define LOG2E2 2.8853900817779268f

// ---------------------------------------------------------------------------
__global__ void k0_zero() {
    if (threadIdx.x < NCHUNK) g_cnt[threadIdx.x] = 0u;
}

// one LSTM step (verbatim r8 math); GV = pre-staged G value (revolutions)
#define QSTEP(GV) do {                                                        \
    float sA = fmaf(H[0],Whp[0],fmaf(H[1],Whp[1],fmaf(H[2],Whp[2],H[3]*Whp[3]))); \
    float sB = fmaf(H[4],Whp[4],fmaf(H[5],Whp[5],fmaf(H[6],Whp[6],H[7]*Whp[7]))); \
    float cs = __builtin_amdgcn_cosf((GV) + sA + sB);                         \
    float p = cs, s;                                                          \
    s = updpf<DPP_SHR(1)>(1.0f, p); p *= (m1 ? s : 1.0f);                     \
    s = updpf<DPP_SHR(2)>(1.0f, p); p *= (m2 ? s : 1.0f);                     \
    s = updpf<DPP_SHR(4)>(1.0f, p); p *= (m4 ? s : 1.0f);                     \
    float v = jz ? 1.0f : cs;                                                 \
    v *= updpf<DPP_QP(1,0,3,2)>(v, v);                                        \
    v *= updpf<DPP_QP(2,3,0,1)>(v, v);                                        \
    float xl = updpf<DPP_SHL(4)>(v, v);                                       \
    float xr = updpf<DPP_SHR(4)>(v, v);                                       \
    v *= (m4 ? xr : xl);                                                      \
    float qv = jz ? v : p;                                                    \
    float act = fmaf(sk, frcp(1.0f + fexp2(ek * qv)), ok);                    \
    float A_  = act;                                                          \
    float B8  = updpf<DPP_ROR(8)>(A_, A_);                                    \
    float C16 = xor16f(A_);                                                   \
    float D24 = updpf<DPP_ROR(8)>(C16, C16);                                  \
    float fv = (g==0) ? A_ : (g==1) ? B8 : (g==2) ? C16 : D24;                \
    float iv = (g==1) ? A_ : (g==0) ? B8 : (g==3) ? C16 : D24;                \
    float uv = (g==2) ? A_ : (g==3) ? B8 : (g==0) ? C16 : D24;                \
    float ov = (g==3) ? A_ : (g==2) ? B8 : (g==1) ? C16 : D24;                \
    c_own = fmaf(fv, c_own, iv * uv);                                         \
    float tc = fmaf(-2.0f, frcp(1.0f + fexp2(LOG2E2 * c_own)), 1.0f);         \
    h_own = ov * tc;                                                          \
    H[0] = h_own;                                                             \
    H[1] = updpf<DPP_QP(1,0,3,2)>(H[0], H[0]);                                \
    H[2] = updpf<DPP_QP(2,3,0,1)>(H[0], H[0]);                                \
    H[3] = updpf<DPP_QP(2,3,0,1)>(H[1], H[1]);                                \
    _Pragma("unroll")                                                         \
    for (int rr = 0; rr < 4; ++rr) {                                          \
        float yl = updpf<DPP_SHL(4)>(H[rr], H[rr]);                           \
        float yr = updpf<DPP_SHR(4)>(H[rr], H[rr]);                           \
        H[4 + rr] = m4 ? yr : yl;                                             \
    }                                                                         \
} while (0)

// ---------------------------------------------------------------------------
// Fused producer-consumer kernel.
//   blocks 0..127   : persistent k1 (4 units of 64 rows each, t-ascending ->
//                     chunk completion staggers in 4 phases). W staged once.
//   blocks 128..255 : k2 consumer (1 wave), streams G per 8-step chunk from
//                     global with register double-buffer, gated on g_cnt.
// ---------------------------------------------------------------------------
__global__ __launch_bounds__(256)
void k_fused(const int* __restrict__ sent, const float* __restrict__ emb,
             const float* __restrict__ Wf, const float* __restrict__ Wi,
             const float* __restrict__ Wu, const float* __restrict__ Wo,
             const float* __restrict__ bf, const float* __restrict__ bi,
             const float* __restrict__ bu, const float* __restrict__ bo,
             const float* __restrict__ thf, const float* __restrict__ thi,
             const float* __restrict__ thu, const float* __restrict__ tho,
             float* __restrict__ G, float* __restrict__ out)
{
    __shared__ short Wlds[32][WROW];     // 33.5 KB bf16, [c][k] (k1 role only)

    const int tid = threadIdx.x;

    if (blockIdx.x < K1BLK) {
        // =================== k1 role: persistent producer ===================
        const int bid = blockIdx.x;

        // ---- stage W -> bf16 LDS once ----
        {
            const int c = tid & 31, seg = tid >> 5;
            const int gg = c >> 3, j = c & 7;
            const float* W = (gg==0) ? Wf : (gg==1) ? Wi : (gg==2) ? Wu : Wo;
            const float* src = W + (size_t)j * DIN + seg * 64;
            #pragma unroll
            for (int pp = 0; pp < 8; ++pp) {
                float4 u = *reinterpret_cast<const float4*>(src + pp * 8);
                float4 v = *reinterpret_cast<const float4*>(src + pp * 8 + 4);
                bf16x8 pk;
                pk[0]=f2bf(u.x); pk[1]=f2bf(u.y); pk[2]=f2bf(u.z); pk[3]=f2bf(u.w);
                pk[4]=f2bf(v.x); pk[5]=f2bf(v.y); pk[6]=f2bf(v.z); pk[7]=f2bf(v.w);
                *reinterpret_cast<bf16x8*>(&Wlds[c][seg * 64 + pp * 8]) = pk;
            }
        }

        const int l  = tid & 63;
        const int w  = tid >> 6;
        const int lm = l & 15;
        const int q  = l >> 4;

        float bc[2];
        #pragma unroll
        for (int n = 0; n < 2; ++n) {
            int c = n * 16 + lm;
            int gg = c >> 3, j = c & 7;
            const float* B  = (gg==0) ? bf  : (gg==1) ? bi  : (gg==2) ? bu  : bo;
            const float* Th = (gg==0) ? thf : (gg==1) ? thi : (gg==2) ? thu : tho;
            bc[n] = (B[j] + Th[j]) * INV2PI;
        }
        __syncthreads();

        #pragma unroll 1
        for (int u = bid; u < NUNITS; u += K1BLK) {
            const int row0  = u * 64;
            const int mytok = sent[row0 + w * 16 + lm];
            const float* arow = emb + (size_t)mytok * EMBED;

            f32x4 acc0 = {0.f,0.f,0.f,0.f};
            f32x4 acc1 = {0.f,0.f,0.f,0.f};
            #pragma unroll
            for (int kc = 0; kc < 16; ++kc) {
                const int kl = kc * 32 + q * 8;
                float4 uu = *reinterpret_cast<const float4*>(arow + kl);
                float4 vv = *reinterpret_cast<const float4*>(arow + kl + 4);
                bf16x8 a;
                a[0]=f2bf(uu.x); a[1]=f2bf(uu.y); a[2]=f2bf(uu.z); a[3]=f2bf(uu.w);
                a[4]=f2bf(vv.x); a[5]=f2bf(vv.y); a[6]=f2bf(vv.z); a[7]=f2bf(vv.w);
                bf16x8 b0 = *reinterpret_cast<const bf16x8*>(&Wlds[lm][kl]);
                bf16x8 b1 = *reinterpret_cast<const bf16x8*>(&Wlds[16 + lm][kl]);
                acc0 = __builtin_amdgcn_mfma_f32_16x16x32_bf16(a, b0, acc0, 0, 0, 0);
                acc1 = __builtin_amdgcn_mfma_f32_16x16x32_bf16(a, b1, acc1, 0, 0, 0);
            }
            #pragma unroll
            for (int rr = 0; rr < 4; ++rr) {
                int row = row0 + w * 16 + q * 4 + rr;
                G[(size_t)row * GSTR + 0  + lm] = fmaf(acc0[rr], INV2PI, bc[0]);
                G[(size_t)row * GSTR + 16 + lm] = fmaf(acc1[rr], INV2PI, bc[1]);
            }
            __threadfence();
            __syncthreads();
            if (tid == 0)
                __hip_atomic_fetch_add(&g_cnt[u >> 5], 1u,
                                       __ATOMIC_RELEASE, __HIP_MEMORY_SCOPE_AGENT);
        }
        return;
    }

    // ===================== k2 role: streaming consumer ======================
    if (tid >= 64) return;               // 1 wave; no barriers on this path

    const int kb  = blockIdx.x - K1BLK;  // 0..127
    const int l32 = tid & 31;
    const int g   = l32 >> 3;            // gate 0..3 (f,i,u,o)
    const int j   = l32 & 7;             // qubit
    const int r   = tid >> 5;            // row-in-block
    const int b   = kb * 2 + r;

    const float* Wsel = (g==0) ? Wf : (g==1) ? Wi : (g==2) ? Wu : Wo;
    float Whp[8];
    #pragma unroll
    for (int rr = 0; rr < 8; ++rr)
        Whp[rr] = Wsel[j * DIN + EMBED + (j ^ rr)] * INV2PI;

    float H[8];
    #pragma unroll
    for (int rr = 0; rr < 8; ++rr) H[rr] = 0.f;
    float c_own = 0.f, h_own = 0.f;

    const bool m1 = (j >= 1), m2 = (j >= 2), m4 = (j >= 4), jz = (j == 0);
    const bool isU = (g == 2);
    const float ek = isU ? LOG2E2 : -LOG2E;
    const float sk = isU ? -2.0f  : 1.0f;
    const float ok = isU ? 1.0f   : 0.0f;

    const float* gptr = G + (size_t)b * GSTR + l32;   // + t*8192 per step

    auto cwait = [&](int c) {
        while (__hip_atomic_load(&g_cnt[c], __ATOMIC_ACQUIRE,
                                 __HIP_MEMORY_SCOPE_AGENT) < (unsigned)UNITS_PER_CHUNK)
            __builtin_amdgcn_s_sleep(2);
    };

    float fA[8], fB[8];
    cwait(0);
    #pragma unroll
    for (int k = 0; k < 8; ++k) fA[k] = gptr[(size_t)k * 8192];
    cwait(1);
    #pragma unroll
    for (int k = 0; k < 8; ++k) fB[k] = gptr[(size_t)(8 + k) * 8192];

    #pragma unroll 1
    for (int cp = 0; cp < 7; ++cp) {
        // compute chunk 2cp from A (B's loads still in flight beneath)
        #pragma unroll
        for (int k = 0; k < 8; ++k) QSTEP(fA[k]);
        cwait(2 * cp + 2);
        #pragma unroll
        for (int k = 0; k < 8; ++k)
            fA[k] = gptr[((size_t)(2 * cp + 2) * 8 + k) * 8192];
        // compute chunk 2cp+1 from B
        #pragma unroll
        for (int k = 0; k < 8; ++k) QSTEP(fB[k]);
        cwait(2 * cp + 3);
        #pragma unroll
        for (int k = 0; k < 8; ++k)
            fB[k] = gptr[((size_t)(2 * cp + 3) * 8 + k) * 8192];
    }
    #pragma unroll
    for (int k = 0; k < 8; ++k) QSTEP(fA[k]);   // chunk 14
    #pragma unroll
    for (int k = 0; k < 8; ++k) QSTEP(fB[k]);   // chunk 15

    if (l32 < 8) out[b * NQ + j] = h_own;
}

// ---------------------------------------------------------------------------
extern "C" void kernel_launch(void* const* d_in, const int* in_sizes, int n_in,
                              void* d_out, int out_size, void* d_ws, size_t ws_size,
                              hipStream_t stream)
{
    const int*   sent = (const int*)  d_in[0];
    // d_in[1] = features : unused by the reference
    const float* emb  = (const float*)d_in[2];
    const float* Wf   = (const float*)d_in[3];
    const float* bf   = (const float*)d_in[4];
    const float* Wi   = (const float*)d_in[5];
    const float* bi   = (const float*)d_in[6];
    const float* Wu   = (const float*)d_in[7];
    const float* bu   = (const float*)d_in[8];
    const float* Wo   = (const float*)d_in[9];
    const float* bo   = (const float*)d_in[10];
    const float* thf  = (const float*)d_in[11];
    const float* thi  = (const float*)d_in[12];
    const float* thu  = (const float*)d_in[13];
    const float* tho  = (const float*)d_in[14];
    float* out = (float*)d_out;

    float* G = (float*)d_ws;   // 32768 * 32 * 4B = 4 MB

    k0_zero<<<1, 64, 0, stream>>>();
    k_fused<<<K1BLK + BATCHN/2, 256, 0, stream>>>(
        sent, emb, Wf, Wi, Wu, Wo, bf, bi, bu, bo,
        thf, thi, thu, tho, G, out);
}

// Round 10
// 75.526 us; speedup vs baseline: 2.4780x; 2.4780x over previous
//
#include <hip/hip_runtime.h>
#include <hip/hip_bf16.h>

#define NQ     8
#define SEQL   128
#define BATCHN 256
#define EMBED  512
#define DIN    520          // EMBED + NQ
#define NROWS  (SEQL*BATCHN) // 32768
#define GSTR   32           // 4 gates * 8 qubits
#define INV2PI 0.15915494309189535f
#define WROW   524          // Wlds padded row (shorts)

typedef __attribute__((ext_vector_type(8))) short  bf16x8;
typedef __attribute__((ext_vector_type(4))) float  f32x4;

__device__ __forceinline__ short f2bf(float f) {
    union { __hip_bfloat16 h; short s; } u;
    u.h = __float2bfloat16(f);          // RNE convert
    return u.s;
}

// ---------------------------------------------------------------------------
// DPP helpers: row_shr:N -> lane i gets i-N (out-of-row -> old);
//              row_shl:N -> lane i gets i+N; quad_perm absolute within quads
// ---------------------------------------------------------------------------
#define DPP_QP(a,b,c,d) ((a)|((b)<<2)|((c)<<4)|((d)<<6))
#define DPP_SHL(n) (0x100+(n))
#define DPP_SHR(n) (0x110+(n))

template<int CTRL>
__device__ __forceinline__ float updpf(float old_, float src) {
    return __int_as_float(__builtin_amdgcn_update_dpp(
        __float_as_int(old_), __float_as_int(src), CTRL, 0xF, 0xF, false));
}

__device__ __forceinline__ float frcp(float x) { return __builtin_amdgcn_rcpf(x); }
__device__ __forceinline__ float fexp2(float x) { return __builtin_amdgcn_exp2f(x); }

#define LOG2E  1.4426950408889634f
#define LOG2E2 2.8853900817779268f

// ---------------------------------------------------------------------------
// Kernel 1 (MFMA, r8-proven verbatim):
//   G[row*32+c] = (emb[sent[row]].W_c + b_c + th_c) * INV2PI
// ---------------------------------------------------------------------------
__global__ __launch_bounds__(256)
void k1_gates(const int* __restrict__ sent, const float* __restrict__ emb,
              const float* __restrict__ Wf, const float* __restrict__ Wi,
              const float* __restrict__ Wu, const float* __restrict__ Wo,
              const float* __restrict__ bf, const float* __restrict__ bi,
              const float* __restrict__ bu, const float* __restrict__ bo,
              const float* __restrict__ thf, const float* __restrict__ thi,
              const float* __restrict__ thu, const float* __restrict__ tho,
              float* __restrict__ G)
{
    __shared__ short Wlds[32][WROW];     // 33.5 KB bf16, [c][k]

    const int tid  = threadIdx.x;
    const int row0 = blockIdx.x * 64;

    // ---- stage W -> bf16 LDS: c = tid&31, segment = tid>>5 (64 floats) ----
    {
        const int c = tid & 31, seg = tid >> 5;
        const int g = c >> 3, j = c & 7;
        const float* W = (g==0) ? Wf : (g==1) ? Wi : (g==2) ? Wu : Wo;
        const float* src = W + (size_t)j * DIN + seg * 64;
        #pragma unroll
        for (int p = 0; p < 8; ++p) {
            float4 u = *reinterpret_cast<const float4*>(src + p * 8);
            float4 v = *reinterpret_cast<const float4*>(src + p * 8 + 4);
            bf16x8 pk;
            pk[0]=f2bf(u.x); pk[1]=f2bf(u.y); pk[2]=f2bf(u.z); pk[3]=f2bf(u.w);
            pk[4]=f2bf(v.x); pk[5]=f2bf(v.y); pk[6]=f2bf(v.z); pk[7]=f2bf(v.w);
            *reinterpret_cast<bf16x8*>(&Wlds[c][seg * 64 + p * 8]) = pk;
        }
    }

    const int l  = tid & 63;             // lane
    const int w  = tid >> 6;             // wave -> M-tile
    const int lm = l & 15;               // row-in-tile / col-in-tile
    const int q  = l >> 4;               // k-quarter (8 elems)

    const int    mytok = sent[row0 + w * 16 + lm];
    const float* arow  = emb + (size_t)mytok * EMBED;

    // bias/theta for the two N-tiles (c = n*16 + lm)
    float bc[2];
    #pragma unroll
    for (int n = 0; n < 2; ++n) {
        int c = n * 16 + lm;
        int g = c >> 3, j = c & 7;
        const float* B  = (g==0) ? bf  : (g==1) ? bi  : (g==2) ? bu  : bo;
        const float* Th = (g==0) ? thf : (g==1) ? thi : (g==2) ? thu : tho;
        bc[n] = (B[j] + Th[j]) * INV2PI;
    }
    __syncthreads();

    f32x4 acc0 = {0.f,0.f,0.f,0.f};
    f32x4 acc1 = {0.f,0.f,0.f,0.f};

    #pragma unroll
    for (int kc = 0; kc < 16; ++kc) {
        const int kl = kc * 32 + q * 8;
        float4 u = *reinterpret_cast<const float4*>(arow + kl);
        float4 v = *reinterpret_cast<const float4*>(arow + kl + 4);
        bf16x8 a;
        a[0]=f2bf(u.x); a[1]=f2bf(u.y); a[2]=f2bf(u.z); a[3]=f2bf(u.w);
        a[4]=f2bf(v.x); a[5]=f2bf(v.y); a[6]=f2bf(v.z); a[7]=f2bf(v.w);
        bf16x8 b0 = *reinterpret_cast<const bf16x8*>(&Wlds[lm][kl]);
        bf16x8 b1 = *reinterpret_cast<const bf16x8*>(&Wlds[16 + lm][kl]);
        acc0 = __builtin_amdgcn_mfma_f32_16x16x32_bf16(a, b0, acc0, 0, 0, 0);
        acc1 = __builtin_amdgcn_mfma_f32_16x16x32_bf16(a, b1, acc1, 0, 0, 0);
    }

    // epilogue: C layout col=lm, row=4*q+r ; scale + fused bias/theta
    #pragma unroll
    for (int r = 0; r < 4; ++r) {
        int row = row0 + w * 16 + q * 4 + r;
        G[(size_t)row * GSTR + 0  + lm] = fmaf(acc0[r], INV2PI, bc[0]);
        G[(size_t)row * GSTR + 16 + lm] = fmaf(acc1[r], INV2PI, bc[1]);
    }
}

// ---------------------------------------------------------------------------
// Kernel 2: LSTM recurrence, 2 qubits/lane, 4 rows/wave (64 blocks x 64 thr).
//   lane = r*16 + qp*4 + gate ; qubits {2qp, 2qp+1} ; gate 0..3 = f,i,u,o.
//   - gate gather = 4 quad_perm BROADCASTS (absolute, zero selects)
//   - qubit-pair scan: 2 Hillis-Steele stages + 1 shift, DPP row boundary ==
//     row group -> old=1.0 fill replaces guards
//   - H all-gather: ^4, ^8 butterflies (2 stages)
//   - G streamed from global as float2 with 2-step register prefetch (no LDS)
// ---------------------------------------------------------------------------
__global__ __launch_bounds__(64)
void k2_lstm(const float* __restrict__ G,
             const float* __restrict__ Wf, const float* __restrict__ Wi,
             const float* __restrict__ Wu, const float* __restrict__ Wo,
             float* __restrict__ out)
{
    const int tid  = threadIdx.x;        // 0..63, 1 wave
    const int gate = tid & 3;
    const int qp   = (tid >> 2) & 3;
    const int row  = blockIdx.x * 4 + (tid >> 4);
    const int qa   = 2 * qp;

    const float* Wsel = (gate==0)?Wf:(gate==1)?Wi:(gate==2)?Wu:Wo;

    // weight order matches H-gather register order:
    // P = [2qp, 2qp+1, 2(qp^1), 2(qp^1)+1, 2(qp^2), 2(qp^2)+1, 2(qp^3), 2(qp^3)+1]
    int P[8];
    P[0]=2*qp;     P[1]=2*qp+1;     P[2]=2*(qp^1); P[3]=2*(qp^1)+1;
    P[4]=2*(qp^2); P[5]=2*(qp^2)+1; P[6]=2*(qp^3); P[7]=2*(qp^3)+1;

    float Wa[8], Wb[8];
    #pragma unroll
    for (int k = 0; k < 8; ++k) {
        Wa[k] = Wsel[(size_t)qa       * DIN + EMBED + P[k]] * INV2PI;
        Wb[k] = Wsel[(size_t)(qa + 1) * DIN + EMBED + P[k]] * INV2PI;
    }

    float H[8];
    #pragma unroll
    for (int k = 0; k < 8; ++k) H[k] = 0.f;
    float c_a = 0.f, c_b = 0.f, h_a = 0.f, h_b = 0.f;

    const bool isU = (gate == 2);
    const float ek = isU ? LOG2E2 : -LOG2E;
    const float sk = isU ? -2.0f  : 1.0f;
    const float ok = isU ? 1.0f   : 0.0f;
    const bool q0 = (qp == 0), q1 = (qp & 1), q2 = (qp & 2);

    const float* gp = G + (size_t)row * GSTR + gate * 8 + qa;
    float2 fA = *reinterpret_cast<const float2*>(gp);
    float2 fB = *reinterpret_cast<const float2*>(gp + 8192);

    for (int t = 0; t < SEQL; ++t) {
        // 2-deep prefetch (off the dependence chain; L2/L3-resident)
        int tn = (t + 2 < SEQL) ? t + 2 : SEQL - 1;
        float2 nx = *reinterpret_cast<const float2*>(gp + (size_t)tn * 8192);

        // y (revolutions) = G + h-dot, two 2x4 split chains per qubit
        float sa1 = fmaf(H[0],Wa[0], fmaf(H[1],Wa[1], fmaf(H[2],Wa[2], H[3]*Wa[3])));
        float sa2 = fmaf(H[4],Wa[4], fmaf(H[5],Wa[5], fmaf(H[6],Wa[6], H[7]*Wa[7])));
        float sb1 = fmaf(H[0],Wb[0], fmaf(H[1],Wb[1], fmaf(H[2],Wb[2], H[3]*Wb[3])));
        float sb2 = fmaf(H[4],Wb[4], fmaf(H[5],Wb[5], fmaf(H[6],Wb[6], H[7]*Wb[7])));
        float csa = __builtin_amdgcn_cosf((fA.x + sa1) + sa2);
        float csb = __builtin_amdgcn_cosf((fA.y + sb1) + sb2);

        // inclusive prefix over qubit pairs (unguarded: row boundary -> 1.0)
        float pp = csa * csb;
        float x1 = pp * updpf<DPP_SHR(4)>(1.0f, pp);
        float x2 = x1 * updpf<DPP_SHR(8)>(1.0f, x1);
        float lo = updpf<DPP_SHR(4)>(1.0f, x2);      // pairs < qp
        float inca = lo * csa;                        // prefix incl qubit 2qp
        float incb = lo * pp;                         // prefix incl qubit 2qp+1

        // full product of cs_1..cs_7 (qubit-0 output), 2-stage butterfly
        float vp  = q0 ? csb : pp;
        float e1l = updpf<DPP_SHL(4)>(vp, vp);
        float e1r = updpf<DPP_SHR(4)>(vp, vp);
        float e1  = vp * (q1 ? e1r : e1l);
        float e2l = updpf<DPP_SHL(8)>(e1, e1);
        float e2r = updpf<DPP_SHR(8)>(e1, e1);
        float fullp = e1 * (q2 ? e2r : e2l);

        float qva = q0 ? fullp : inca;
        float qvb = incb;

        // activation: u -> tanh, f/i/o -> sigmoid (exp2+rcp)
        float aa = fmaf(sk, frcp(1.0f + fexp2(ek * qva)), ok);
        float ab = fmaf(sk, frcp(1.0f + fexp2(ek * qvb)), ok);

        // gate gather: absolute quad broadcasts, no selects
        float fva = updpf<DPP_QP(0,0,0,0)>(aa, aa);
        float iva = updpf<DPP_QP(1,1,1,1)>(aa, aa);
        float uva = updpf<DPP_QP(2,2,2,2)>(aa, aa);
        float ova = updpf<DPP_QP(3,3,3,3)>(aa, aa);
        float fvb = updpf<DPP_QP(0,0,0,0)>(ab, ab);
        float ivb = updpf<DPP_QP(1,1,1,1)>(ab, ab);
        float uvb = updpf<DPP_QP(2,2,2,2)>(ab, ab);
        float ovb = updpf<DPP_QP(3,3,3,3)>(ab, ab);

        c_a = fmaf(fva, c_a, iva * uva);             // |c| <= 2.07
        c_b = fmaf(fvb, c_b, ivb * uvb);
        float tca = fmaf(-2.0f, frcp(1.0f + fexp2(LOG2E2 * c_a)), 1.0f);
        float tcb = fmaf(-2.0f, frcp(1.0f + fexp2(LOG2E2 * c_b)), 1.0f);
        h_a = ova * tca;
        h_b = ovb * tcb;

        // H all-gather: own pair, ^4 partner pair, then ^8 exchange of all 4
        H[0] = h_a; H[1] = h_b;
        {
            float l0 = updpf<DPP_SHL(4)>(H[0], H[0]);
            float r0 = updpf<DPP_SHR(4)>(H[0], H[0]);
            float l1 = updpf<DPP_SHL(4)>(H[1], H[1]);
            float r1 = updpf<DPP_SHR(4)>(H[1], H[1]);
            H[2] = q1 ? r0 : l0;
            H[3] = q1 ? r1 : l1;
            float a4 = updpf<DPP_SHL(8)>(H[0], H[0]);
            float b4 = updpf<DPP_SHR(8)>(H[0], H[0]);
            float a5 = updpf<DPP_SHL(8)>(H[1], H[1]);
            float b5 = updpf<DPP_SHR(8)>(H[1], H[1]);
            float a6 = updpf<DPP_SHL(8)>(H[2], H[2]);
            float b6 = updpf<DPP_SHR(8)>(H[2], H[2]);
            float a7 = updpf<DPP_SHL(8)>(H[3], H[3]);
            float b7 = updpf<DPP_SHR(8)>(H[3], H[3]);
            H[4] = q2 ? b4 : a4;
            H[5] = q2 ? b5 : a5;
            H[6] = q2 ? b6 : a6;
            H[7] = q2 ? b7 : a7;
        }

        fA = fB; fB = nx;
    }

    if (gate == 0)
        *reinterpret_cast<float2*>(out + (size_t)row * NQ + qa) =
            make_float2(h_a, h_b);
}

// ---------------------------------------------------------------------------
extern "C" void kernel_launch(void* const* d_in, const int* in_sizes, int n_in,
                              void* d_out, int out_size, void* d_ws, size_t ws_size,
                              hipStream_t stream)
{
    const int*   sent = (const int*)  d_in[0];
    // d_in[1] = features : unused by the reference
    const float* emb  = (const float*)d_in[2];
    const float* Wf   = (const float*)d_in[3];
    const float* bf   = (const float*)d_in[4];
    const float* Wi   = (const float*)d_in[5];
    const float* bi   = (const float*)d_in[6];
    const float* Wu   = (const float*)d_in[7];
    const float* bu   = (const float*)d_in[8];
    const float* Wo   = (const float*)d_in[9];
    const float* bo   = (const float*)d_in[10];
    const float* thf  = (const float*)d_in[11];
    const float* thi  = (const float*)d_in[12];
    const float* thu  = (const float*)d_in[13];
    const float* tho  = (const float*)d_in[14];
    float* out = (float*)d_out;

    float* G = (float*)d_ws;   // 32768 * 32 * 4B = 4 MB

    k1_gates<<<NROWS/64, 256, 0, stream>>>(sent, emb, Wf, Wi, Wu, Wo,
                                           bf, bi, bu, bo,
                                           thf, thi, thu, tho, G);
    k2_lstm<<<BATCHN/4, 64, 0, stream>>>(G, Wf, Wi, Wu, Wo, out);
}